// Round 10
// baseline (431.566 us; speedup 1.0000x reference)
//
#include <hip/hip_runtime.h>
#include <hip/hip_fp16.h>

// MoE B=2,N=2048,C=1024,F=4096,E=8,K=2 (T=4096, slots=8192)
// L3-supply-bound GEMMs -> 256x256 tiles (8 waves, 512 thr, 64KB LDS) to
// halve staging traffic. Experts padded to 256-row granularity (even 128-tile
// counts). Serial 2-barrier K-loop, swapped-operand MFMA, swizzled packed tiles.
// r9 bugfix: STAGE4 now stages the FULL 16KB of each tile (2 x 16B per thread
// per tile; r9 staged only half -> uninit LDS -> NaN).

#define T_TOK 4096
#define C_DIM 1024
#define F_DIM 4096
#define E_NUM 8
#define MAXT 80            // 128-row tiles (worst case with 256-granularity pad)
#define NP   (MAXT * 128)
#define TILE_H 8192        // halfs per 128x64 tile (16KB)

typedef float f32x4 __attribute__((ext_vector_type(4)));
typedef _Float16 half8 __attribute__((ext_vector_type(8)));
typedef _Float16 half4 __attribute__((ext_vector_type(4)));

#define AS1 __attribute__((address_space(1)))
#define AS3 __attribute__((address_space(3)))

__device__ __forceinline__ int swz(int r, int ec) { return ec ^ ((r & 7) << 3); }

__device__ __forceinline__ half8 cvt8(float4 f0, float4 f1) {
  half8 hv;
  hv[0] = (_Float16)f0.x; hv[1] = (_Float16)f0.y; hv[2] = (_Float16)f0.z; hv[3] = (_Float16)f0.w;
  hv[4] = (_Float16)f1.x; hv[5] = (_Float16)f1.y; hv[6] = (_Float16)f1.z; hv[7] = (_Float16)f1.w;
  return hv;
}

// bijective XCD chunk swizzle (m204)
__device__ __forceinline__ int xcd_swz(int bid, int nwg) {
  int xcd = bid & 7, rest = bid >> 3;
  int q = nwg >> 3, r = nwg & 7;
  return (xcd < r ? xcd * (q + 1) : r * (q + 1) + (xcd - r) * q) + rest;
}

// ---------------- Router
__global__ __launch_bounds__(256) void router_kernel(
    const float* __restrict__ x, const float* __restrict__ rw,
    int* __restrict__ top_idx, float* __restrict__ top_w)
{
  int t = blockIdx.x * 4 + (threadIdx.x >> 6);
  int lane = threadIdx.x & 63;
  const float* xr = x + (size_t)t * C_DIM;
  float acc[E_NUM];
#pragma unroll
  for (int e = 0; e < E_NUM; ++e) acc[e] = 0.f;
  for (int j = 0; j < C_DIM / 64; ++j) {
    int c = j * 64 + lane;
    float xv = xr[c];
#pragma unroll
    for (int e = 0; e < E_NUM; ++e) acc[e] += xv * rw[e * C_DIM + c];
  }
#pragma unroll
  for (int e = 0; e < E_NUM; ++e) {
    float v = acc[e];
#pragma unroll
    for (int off = 32; off > 0; off >>= 1) v += __shfl_xor(v, off);
    acc[e] = v;
  }
  if (lane == 0) {
    float mx = acc[0];
    for (int e = 1; e < E_NUM; ++e) mx = fmaxf(mx, acc[e]);
    float p[E_NUM]; float Z = 0.f;
    for (int e = 0; e < E_NUM; ++e) { p[e] = expf(acc[e] - mx); Z += p[e]; }
    int b0 = 0;
    for (int e = 1; e < E_NUM; ++e) if (p[e] > p[b0]) b0 = e;
    int b1i = -1; float pb = -1.f;
    for (int e = 0; e < E_NUM; ++e) if (e != b0 && p[e] > pb) { pb = p[e]; b1i = e; }
    float p0 = p[b0] / Z, p1 = pb / Z;
    float s = p0 + p1 + 1e-9f;
    top_idx[t * 2 + 0] = b0;
    top_idx[t * 2 + 1] = b1i;
    top_w[t * 2 + 0] = p0 / s;
    top_w[t * 2 + 1] = p1 / s;
  }
}

// ---------------- Lists: tile counts padded to EVEN (256-row granularity)
__global__ void build_lists(const int* __restrict__ top_idx,
                            int* __restrict__ rows_g, int* __restrict__ counts,
                            int* __restrict__ tile_off, int* __restrict__ inv)
{
  int e = threadIdx.x >> 6;
  int lane = threadIdx.x & 63;
  int cnt = 0;
  for (int t0 = 0; t0 < T_TOK; t0 += 64) {
    int t = t0 + lane;
    bool sel = (top_idx[t * 2] == e) || (top_idx[t * 2 + 1] == e);
    cnt += __popcll(__ballot(sel));
  }
  if (lane == 0) counts[e] = cnt;
  __syncthreads();
  if (threadIdx.x == 0) {
    int o = 0;
    for (int i = 0; i < E_NUM; ++i) { tile_off[i] = o; o += 2 * ((counts[i] + 255) >> 8); }
    tile_off[E_NUM] = o;
  }
  __syncthreads();
  int base = tile_off[e] * 128;
  int pos = 0;
  for (int t0 = 0; t0 < T_TOK; t0 += 64) {
    int t = t0 + lane;
    int i0 = top_idx[t * 2], i1 = top_idx[t * 2 + 1];
    bool sel = (i0 == e) || (i1 == e);
    unsigned long long mask = __ballot(sel);
    if (sel) {
      int p = pos + __popcll(mask & ((1ull << lane) - 1ull));
      int slot = t * 2 + ((i0 == e) ? 0 : 1);
      rows_g[base + p] = slot;
      inv[slot] = (e << 16) | (base + p);
    }
    pos += __popcll(mask);
  }
}

// ---------------- Gather x -> tiled swizzled fp16
__global__ __launch_bounds__(256) void gather_x(
    const float* __restrict__ x, const int* __restrict__ rows_g,
    const int* __restrict__ counts, const int* __restrict__ tile_off,
    _Float16* __restrict__ xg)
{
  unsigned g = blockIdx.x * 256 + threadIdx.x;
  unsigned p = g >> 7, ccr = g & 127;
  int gt = p >> 7, r = p & 127;
  int kc = ccr >> 3, c8 = ccr & 7;
  int e = -1;
#pragma unroll
  for (int i = 0; i < E_NUM; ++i)
    if (gt >= tile_off[i] && gt < tile_off[i + 1]) e = i;
  half8 hv = {};
  if (e >= 0) {
    int nrem = counts[e] - (gt - tile_off[e]) * 128;
    if (r < nrem) {
      int t = rows_g[p] >> 1;
      const float4* s = reinterpret_cast<const float4*>(x + (size_t)t * C_DIM + kc * 64 + c8 * 8);
      hv = cvt8(s[0], s[1]);
    }
  }
  *reinterpret_cast<half8*>(xg + ((size_t)gt * 16 + kc) * TILE_H + r * 64 + ((c8 ^ (r & 7)) << 3)) = hv;
}

// ---------------- merged w1+w2 -> tiled fp16, DST-LINEAR (coalesced writes)
__global__ __launch_bounds__(256) void cvt_w(
    const float* __restrict__ w1, const float* __restrict__ w2,
    _Float16* __restrict__ w1t, _Float16* __restrict__ w2t,
    int ch, int Fc, int lgnftl, int lgnkc, unsigned halfChunks)
{
  unsigned g = blockIdx.x * 256 + threadIdx.x;
  if (g < halfChunks) {
    unsigned tile = g >> 10;
    unsigned kc = tile & 15;
    unsigned et = tile >> 4;
    unsigned ftl = et & ((1u << lgnftl) - 1);
    unsigned e = et >> lgnftl;
    unsigned r = (g >> 3) & 127;
    unsigned sc = g & 7;
    unsigned c8 = sc ^ (r & 7);
    unsigned frow = ftl * 128 + r;
    const float4* s = reinterpret_cast<const float4*>(
        w1 + ((size_t)e * F_DIM + ch * Fc + frow) * C_DIM + kc * 64 + c8 * 8);
    *reinterpret_cast<half8*>(w1t + (size_t)g * 8) = cvt8(s[0], s[1]);
  } else {
    unsigned g2 = g - halfChunks;
    unsigned tile = g2 >> 10;
    unsigned kc = tile & ((1u << lgnkc) - 1);
    unsigned et = tile >> lgnkc;
    unsigned ct = et & 7;
    unsigned e = et >> 3;
    unsigned r = (g2 >> 3) & 127;
    unsigned sc = g2 & 7;
    unsigned c8 = sc ^ (r & 7);
    unsigned c = ct * 128 + r;
    const float4* s = reinterpret_cast<const float4*>(
        w2 + ((size_t)e * C_DIM + c) * F_DIM + ch * Fc + kc * 64 + c8 * 8);
    *reinterpret_cast<half8*>(w2t + (size_t)g2 * 8) = cvt8(s[0], s[1]);
  }
}

// ======== 256x256 tile machinery: 512 thr, 8 waves (2 row x 4 col) ========
// LDS: As = 2 packed 128x64 tiles, Bs = 2 packed 128x64 tiles (64KB total).
// Each thread stages 2 x 16B per tile (8 loads total) -> full 16KB per tile.
#define STAGE4(a0_, a1_, b0_, b1_)                                                \
  {                                                                               \
    _Pragma("unroll")                                                             \
    for (int i_ = 0; i_ < 2; ++i_) {                                              \
      int o_ = tid * 8 + i_ * 4096;                                               \
      __builtin_amdgcn_global_load_lds((const AS1 void*)((a0_) + o_),             \
          (AS3 void*)(&As[o_]), 16, 0, 0);                                        \
      __builtin_amdgcn_global_load_lds((const AS1 void*)((a1_) + o_),             \
          (AS3 void*)(&As[8192 + o_]), 16, 0, 0);                                 \
      __builtin_amdgcn_global_load_lds((const AS1 void*)((b0_) + o_),             \
          (AS3 void*)(&Bs[o_]), 16, 0, 0);                                        \
      __builtin_amdgcn_global_load_lds((const AS1 void*)((b1_) + o_),             \
          (AS3 void*)(&Bs[8192 + o_]), 16, 0, 0);                                 \
    }                                                                             \
  }

// SWAPPED operands: mfma(bF, aF) -> D rows = f/c (reg-indexed), cols = tokens.
// Wave (wr,wc): rows [wr*128,+128) from A-tile wr, cols [wc*64,+64) of 256.
#define COMPUTE256()                                                              \
  _Pragma("unroll")                                                               \
  for (int kk = 0; kk < 64; kk += 32) {                                           \
    const int klo = kk + (lane >> 4) * 8;                                         \
    half8 aF[8], bF[4];                                                           \
    _Pragma("unroll")                                                             \
    for (int m = 0; m < 8; ++m) {                                                 \
      int r = m * 16 + (lane & 15);                                               \
      aF[m] = *reinterpret_cast<const half8*>(&As[wr * 8192 + r * 64 + swz(r, klo)]); \
    }                                                                             \
    _Pragma("unroll")                                                             \
    for (int n = 0; n < 4; ++n) {                                                 \
      int rb = (wc & 1) * 64 + n * 16 + (lane & 15);                              \
      bF[n] = *reinterpret_cast<const half8*>(&Bs[(wc >> 1) * 8192 + rb * 64 + swz(rb, klo)]); \
    }                                                                             \
    _Pragma("unroll")                                                             \
    for (int m = 0; m < 8; ++m)                                                   \
      _Pragma("unroll")                                                           \
      for (int n = 0; n < 4; ++n)                                                 \
        acc[m][n] = __builtin_amdgcn_mfma_f32_16x16x32_f16(bF[n], aF[m], acc[m][n], 0, 0, 0); \
  }

// ---------------- GEMM1: ht[pos, f] = relu(xg[pos] . w1t[e][f] + b1)
// 256x256 tile: A = xg tiles {gt, gt+1}, B = w1t tiles {2ft, 2ft+1}
__global__ __launch_bounds__(512, 2) void gemm1_kernel(
    const _Float16* __restrict__ xg, const _Float16* __restrict__ w1t,
    const float* __restrict__ b1, const int* __restrict__ tile_off,
    _Float16* __restrict__ ht, int ch, int Fc)
{
  const int NFT = Fc >> 8;
  const int wgid = xcd_swz(blockIdx.x, gridDim.x);
  const int grp = wgid / (4 * NFT);
  const int rem = wgid - grp * 4 * NFT;
  const int ft = rem >> 2;
  const int gt = (grp * 4 + (rem & 3)) * 2;
  if (gt >= tile_off[E_NUM]) return;
  int e = 0;
  while (gt >= tile_off[e + 1]) ++e;
  const int nftl = Fc >> 7;
  const _Float16* At0 = xg + (size_t)gt * 16 * TILE_H;
  const _Float16* At1 = xg + (size_t)(gt + 1) * 16 * TILE_H;
  const _Float16* Bt0 = w1t + (size_t)(e * nftl + 2 * ft) * 16 * TILE_H;
  const _Float16* Bt1 = w1t + (size_t)(e * nftl + 2 * ft + 1) * 16 * TILE_H;

  __shared__ __align__(16) _Float16 As[2 * TILE_H];
  __shared__ __align__(16) _Float16 Bs[2 * TILE_H];

  const int tid = threadIdx.x;
  const int lane = tid & 63;
  const int wave = tid >> 6;
  const int wr = wave >> 2, wc = wave & 3;

  f32x4 acc[8][4];
#pragma unroll
  for (int m = 0; m < 8; ++m)
#pragma unroll
    for (int n = 0; n < 4; ++n) acc[m][n] = (f32x4){0.f, 0.f, 0.f, 0.f};

  for (int kc = 0; kc < 16; ++kc) {
    size_t ko = (size_t)kc * TILE_H;
    STAGE4(At0 + ko, At1 + ko, Bt0 + ko, Bt1 + ko);
    __syncthreads();
    COMPUTE256();
    __syncthreads();
  }

  // epilogue: lane holds 4 consecutive f per reg -> 8B stores (pad rows written, never read)
  const int nkcF = Fc >> 6;
  const int gtw = gt + wr;
  const float* b1e = b1 + e * F_DIM + ch * Fc;
#pragma unroll
  for (int m = 0; m < 8; ++m) {
    int tok = m * 16 + (lane & 15);
#pragma unroll
    for (int n = 0; n < 4; ++n) {
      int flb = ft * 256 + wc * 64 + n * 16 + ((lane >> 4) << 2);
      float4 bv = *reinterpret_cast<const float4*>(b1e + flb);
      half4 hv;
      hv[0] = (_Float16)fmaxf(acc[m][n][0] + bv.x, 0.f);
      hv[1] = (_Float16)fmaxf(acc[m][n][1] + bv.y, 0.f);
      hv[2] = (_Float16)fmaxf(acc[m][n][2] + bv.z, 0.f);
      hv[3] = (_Float16)fmaxf(acc[m][n][3] + bv.w, 0.f);
      *reinterpret_cast<half4*>(
          ht + ((size_t)gtw * nkcF + (flb >> 6)) * TILE_H + tok * 64 +
          ((((flb >> 3) & 7) ^ (tok & 7)) << 3) + (flb & 7)) = hv;
    }
  }
}

// ---------------- GEMM2: y[ks][pos][c] (+)= ht[pos] . w2t[e][c]
// 256x256 tile: A = ht tiles {gt, gt+1}, B = w2t tiles {2ct2, 2ct2+1}, K split kspl
__global__ __launch_bounds__(512, 2) void gemm2_kernel(
    const _Float16* __restrict__ ht, const _Float16* __restrict__ w2t,
    const int* __restrict__ tile_off, _Float16* __restrict__ y,
    int Fc, int kspl, int accum)
{
  const int wgid = xcd_swz(blockIdx.x, gridDim.x);
  const int NCMB = 4 * kspl;
  const int grp = wgid / (4 * NCMB);
  const int rem = wgid - grp * 4 * NCMB;
  const int cmb = rem >> 2;
  const int gt = (grp * 4 + (rem & 3)) * 2;
  if (gt >= tile_off[E_NUM]) return;
  const int ct2 = cmb & 3;
  const int ks = cmb >> 2;
  int e = 0;
  while (gt >= tile_off[e + 1]) ++e;
  const int nkc = Fc >> 6;
  const int klen = nkc / kspl;
  const _Float16* At0 = ht + ((size_t)gt * nkc + ks * klen) * TILE_H;
  const _Float16* At1 = ht + ((size_t)(gt + 1) * nkc + ks * klen) * TILE_H;
  const _Float16* Bt0 = w2t + ((size_t)(e * 8 + 2 * ct2) * nkc + ks * klen) * TILE_H;
  const _Float16* Bt1 = w2t + ((size_t)(e * 8 + 2 * ct2 + 1) * nkc + ks * klen) * TILE_H;

  __shared__ __align__(16) _Float16 As[2 * TILE_H];
  __shared__ __align__(16) _Float16 Bs[2 * TILE_H];

  const int tid = threadIdx.x;
  const int lane = tid & 63;
  const int wave = tid >> 6;
  const int wr = wave >> 2, wc = wave & 3;

  f32x4 acc[8][4];
#pragma unroll
  for (int m = 0; m < 8; ++m)
#pragma unroll
    for (int n = 0; n < 4; ++n) acc[m][n] = (f32x4){0.f, 0.f, 0.f, 0.f};

  for (int kc = 0; kc < klen; ++kc) {
    size_t ko = (size_t)kc * TILE_H;
    STAGE4(At0 + ko, At1 + ko, Bt0 + ko, Bt1 + ko);
    __syncthreads();
    COMPUTE256();
    __syncthreads();
  }

  _Float16* yk = y + ((size_t)(ks * MAXT + gt + wr) * 128) * C_DIM;
#pragma unroll
  for (int m = 0; m < 8; ++m) {
    int tok = m * 16 + (lane & 15);
#pragma unroll
    for (int n = 0; n < 4; ++n) {
      int cb = ct2 * 256 + wc * 64 + n * 16 + ((lane >> 4) << 2);
      half4* p = reinterpret_cast<half4*>(yk + (size_t)tok * C_DIM + cb);
      half4 hv;
      if (accum) {
        half4 old = *p;
        hv[0] = (_Float16)(acc[m][n][0] + (float)old[0]);
        hv[1] = (_Float16)(acc[m][n][1] + (float)old[1]);
        hv[2] = (_Float16)(acc[m][n][2] + (float)old[2]);
        hv[3] = (_Float16)(acc[m][n][3] + (float)old[3]);
      } else {
        hv[0] = (_Float16)acc[m][n][0];
        hv[1] = (_Float16)acc[m][n][1];
        hv[2] = (_Float16)acc[m][n][2];
        hv[3] = (_Float16)acc[m][n][3];
      }
      *p = hv;
    }
  }
}

// ---------------- Combine: out[t] = sum_k w_k * (b2[e_k] + sum_ks y[ks][pos_k])
__global__ __launch_bounds__(256) void combine_kernel(
    const _Float16* __restrict__ y, const int* __restrict__ inv,
    const float* __restrict__ top_w, const float* __restrict__ b2,
    float* __restrict__ out, int kspl)
{
  int g = blockIdx.x * 256 + threadIdx.x;
  int t = g >> 7, c8 = (g & 127) << 3;
  float o[8];
#pragma unroll
  for (int i = 0; i < 8; ++i) o[i] = 0.f;
#pragma unroll
  for (int k = 0; k < 2; ++k) {
    int iv = inv[t * 2 + k];
    int e = iv >> 16, pos = iv & 0xffff;
    float w = top_w[t * 2 + k];
    const float4* bb = reinterpret_cast<const float4*>(b2 + e * C_DIM + c8);
    float4 bv0 = bb[0], bv1 = bb[1];
    float s[8] = {bv0.x, bv0.y, bv0.z, bv0.w, bv1.x, bv1.y, bv1.z, bv1.w};
    for (int ks = 0; ks < kspl; ++ks) {
      half8 hv = *reinterpret_cast<const half8*>(
          y + ((size_t)(ks * MAXT * 128 + pos)) * C_DIM + c8);
#pragma unroll
      for (int i = 0; i < 8; ++i) s[i] += (float)hv[i];
    }
#pragma unroll
    for (int i = 0; i < 8; ++i) o[i] += w * s[i];
  }
  float4* op = reinterpret_cast<float4*>(out + (size_t)t * C_DIM + c8);
  op[0] = (float4){o[0], o[1], o[2], o[3]};
  op[1] = (float4){o[4], o[5], o[6], o[7]};
}

extern "C" void kernel_launch(void* const* d_in, const int* in_sizes, int n_in,
                              void* d_out, int out_size, void* d_ws, size_t ws_size,
                              hipStream_t stream)
{
  const float* x  = (const float*)d_in[0];
  const float* rw = (const float*)d_in[1];
  const float* w1 = (const float*)d_in[2];
  const float* b1 = (const float*)d_in[3];
  const float* w2 = (const float*)d_in[4];
  const float* b2 = (const float*)d_in[5];
  float* out = (float*)d_out;

  char* ws = (char*)d_ws;
  size_t off = 0;
  auto carve = [&](size_t bytes) -> void* {
    void* p = ws + off;
    off += (bytes + 255) & ~(size_t)255;
    return p;
  };
  int*   top_idx  = (int*)carve((size_t)T_TOK * 2 * sizeof(int));
  float* top_w    = (float*)carve((size_t)T_TOK * 2 * sizeof(float));
  int*   counts   = (int*)carve(E_NUM * sizeof(int));
  int*   tile_off = (int*)carve((E_NUM + 1) * sizeof(int));
  int*   rows_g   = (int*)carve((size_t)NP * sizeof(int));
  int*   inv      = (int*)carve((size_t)T_TOK * 2 * sizeof(int));
  _Float16* xg    = (_Float16*)carve((size_t)MAXT * 16 * TILE_H * sizeof(_Float16));
  _Float16* y     = (_Float16*)carve((size_t)2 * NP * C_DIM * sizeof(_Float16));
  size_t fixed = off;

  int nchunk = 8;
  const int cands[4] = {1, 2, 4, 8};
  for (int ci = 0; ci < 4; ++ci) {
    int n = cands[ci];
    size_t fc = (size_t)(F_DIM / n);
    size_t w1b = ((size_t)E_NUM * fc * C_DIM * 2 + 255) & ~(size_t)255;
    size_t w2b = ((size_t)E_NUM * C_DIM * fc * 2 + 255) & ~(size_t)255;
    size_t htb = ((size_t)MAXT * (fc >> 6) * TILE_H * 2 + 255) & ~(size_t)255;
    if (fixed + w1b + w2b + htb <= ws_size) { nchunk = n; break; }
  }
  const int Fc = F_DIM / nchunk;
  int lgFc = 0; while ((1 << lgFc) < Fc) ++lgFc;
  _Float16* w1t = (_Float16*)carve((size_t)E_NUM * Fc * C_DIM * sizeof(_Float16));
  _Float16* w2t = (_Float16*)carve((size_t)E_NUM * C_DIM * Fc * sizeof(_Float16));
  _Float16* ht  = (_Float16*)carve((size_t)MAXT * (Fc >> 6) * TILE_H * sizeof(_Float16));

  const int kspl = (Fc >= 2048) ? 2 : 1;

  router_kernel<<<T_TOK / 4, 256, 0, stream>>>(x, rw, top_idx, top_w);
  build_lists<<<1, 512, 0, stream>>>(top_idx, rows_g, counts, tile_off, inv);
  gather_x<<<(MAXT * 128 * 128) / 256, 256, 0, stream>>>(x, rows_g, counts, tile_off, xg);

  const unsigned halfChunks = (unsigned)Fc << 10;   // E*Fc*C/8
  for (int ch = 0; ch < nchunk; ++ch) {
    cvt_w<<<8 * Fc, 256, 0, stream>>>(w1, w2, w1t, w2t, ch, Fc, lgFc - 7, lgFc - 6, halfChunks);
    gemm1_kernel<<<(MAXT / 2) * (Fc / 256), 512, 0, stream>>>(
        xg, w1t, b1, tile_off, ht, ch, Fc);
    gemm2_kernel<<<(MAXT / 2) * 4 * kspl, 512, 0, stream>>>(
        ht, w2t, tile_off, y, Fc, kspl, ch != 0);
  }
  combine_kernel<<<(T_TOK * 128) / 256, 256, 0, stream>>>(y, inv, top_w, b2, out, kspl);
}

// Round 11
// 354.445 us; speedup vs baseline: 1.2176x; 1.2176x over previous
//
#include <hip/hip_runtime.h>
#include <hip/hip_fp16.h>

// MoE B=2,N=2048,C=1024,F=4096,E=8,K=2 (T=4096, slots=8192)
// 256x256 tiles + MINIMUM 2-PHASE pipeline (T3 recipe): double-buffered
// 128KB LDS (dynamic shared), STAGE(next buf) issued BEFORE compute(cur),
// ONE __syncthreads() per K-step (drains vmcnt -> next buffer ready).
// r10 geometry/epilogues kept verbatim (proven correct). gemm2 kspl=4.

#define T_TOK 4096
#define C_DIM 1024
#define F_DIM 4096
#define E_NUM 8
#define MAXT 80            // 128-row tiles (worst case, 256-granularity pad)
#define NP   (MAXT * 128)
#define TILE_H 8192        // halfs per 128x64 packed tile (16KB)

typedef float f32x4 __attribute__((ext_vector_type(4)));
typedef _Float16 half8 __attribute__((ext_vector_type(8)));
typedef _Float16 half4 __attribute__((ext_vector_type(4)));

#define AS1 __attribute__((address_space(1)))
#define AS3 __attribute__((address_space(3)))

__device__ __forceinline__ int swz(int r, int ec) { return ec ^ ((r & 7) << 3); }

__device__ __forceinline__ half8 cvt8(float4 f0, float4 f1) {
  half8 hv;
  hv[0] = (_Float16)f0.x; hv[1] = (_Float16)f0.y; hv[2] = (_Float16)f0.z; hv[3] = (_Float16)f0.w;
  hv[4] = (_Float16)f1.x; hv[5] = (_Float16)f1.y; hv[6] = (_Float16)f1.z; hv[7] = (_Float16)f1.w;
  return hv;
}

// bijective XCD chunk swizzle (m204)
__device__ __forceinline__ int xcd_swz(int bid, int nwg) {
  int xcd = bid & 7, rest = bid >> 3;
  int q = nwg >> 3, r = nwg & 7;
  return (xcd < r ? xcd * (q + 1) : r * (q + 1) + (xcd - r) * q) + rest;
}

// ---------------- Router
__global__ __launch_bounds__(256) void router_kernel(
    const float* __restrict__ x, const float* __restrict__ rw,
    int* __restrict__ top_idx, float* __restrict__ top_w)
{
  int t = blockIdx.x * 4 + (threadIdx.x >> 6);
  int lane = threadIdx.x & 63;
  const float* xr = x + (size_t)t * C_DIM;
  float acc[E_NUM];
#pragma unroll
  for (int e = 0; e < E_NUM; ++e) acc[e] = 0.f;
  for (int j = 0; j < C_DIM / 64; ++j) {
    int c = j * 64 + lane;
    float xv = xr[c];
#pragma unroll
    for (int e = 0; e < E_NUM; ++e) acc[e] += xv * rw[e * C_DIM + c];
  }
#pragma unroll
  for (int e = 0; e < E_NUM; ++e) {
    float v = acc[e];
#pragma unroll
    for (int off = 32; off > 0; off >>= 1) v += __shfl_xor(v, off);
    acc[e] = v;
  }
  if (lane == 0) {
    float mx = acc[0];
    for (int e = 1; e < E_NUM; ++e) mx = fmaxf(mx, acc[e]);
    float p[E_NUM]; float Z = 0.f;
    for (int e = 0; e < E_NUM; ++e) { p[e] = expf(acc[e] - mx); Z += p[e]; }
    int b0 = 0;
    for (int e = 1; e < E_NUM; ++e) if (p[e] > p[b0]) b0 = e;
    int b1i = -1; float pb = -1.f;
    for (int e = 0; e < E_NUM; ++e) if (e != b0 && p[e] > pb) { pb = p[e]; b1i = e; }
    float p0 = p[b0] / Z, p1 = pb / Z;
    float s = p0 + p1 + 1e-9f;
    top_idx[t * 2 + 0] = b0;
    top_idx[t * 2 + 1] = b1i;
    top_w[t * 2 + 0] = p0 / s;
    top_w[t * 2 + 1] = p1 / s;
  }
}

// ---------------- Lists: tile counts padded to EVEN (256-row granularity)
__global__ void build_lists(const int* __restrict__ top_idx,
                            int* __restrict__ rows_g, int* __restrict__ counts,
                            int* __restrict__ tile_off, int* __restrict__ inv)
{
  int e = threadIdx.x >> 6;
  int lane = threadIdx.x & 63;
  int cnt = 0;
  for (int t0 = 0; t0 < T_TOK; t0 += 64) {
    int t = t0 + lane;
    bool sel = (top_idx[t * 2] == e) || (top_idx[t * 2 + 1] == e);
    cnt += __popcll(__ballot(sel));
  }
  if (lane == 0) counts[e] = cnt;
  __syncthreads();
  if (threadIdx.x == 0) {
    int o = 0;
    for (int i = 0; i < E_NUM; ++i) { tile_off[i] = o; o += 2 * ((counts[i] + 255) >> 8); }
    tile_off[E_NUM] = o;
  }
  __syncthreads();
  int base = tile_off[e] * 128;
  int pos = 0;
  for (int t0 = 0; t0 < T_TOK; t0 += 64) {
    int t = t0 + lane;
    int i0 = top_idx[t * 2], i1 = top_idx[t * 2 + 1];
    bool sel = (i0 == e) || (i1 == e);
    unsigned long long mask = __ballot(sel);
    if (sel) {
      int p = pos + __popcll(mask & ((1ull << lane) - 1ull));
      int slot = t * 2 + ((i0 == e) ? 0 : 1);
      rows_g[base + p] = slot;
      inv[slot] = (e << 16) | (base + p);
    }
    pos += __popcll(mask);
  }
}

// ---------------- Gather x -> tiled swizzled fp16
__global__ __launch_bounds__(256) void gather_x(
    const float* __restrict__ x, const int* __restrict__ rows_g,
    const int* __restrict__ counts, const int* __restrict__ tile_off,
    _Float16* __restrict__ xg)
{
  unsigned g = blockIdx.x * 256 + threadIdx.x;
  unsigned p = g >> 7, ccr = g & 127;
  int gt = p >> 7, r = p & 127;
  int kc = ccr >> 3, c8 = ccr & 7;
  int e = -1;
#pragma unroll
  for (int i = 0; i < E_NUM; ++i)
    if (gt >= tile_off[i] && gt < tile_off[i + 1]) e = i;
  half8 hv = {};
  if (e >= 0) {
    int nrem = counts[e] - (gt - tile_off[e]) * 128;
    if (r < nrem) {
      int t = rows_g[p] >> 1;
      const float4* s = reinterpret_cast<const float4*>(x + (size_t)t * C_DIM + kc * 64 + c8 * 8);
      hv = cvt8(s[0], s[1]);
    }
  }
  *reinterpret_cast<half8*>(xg + ((size_t)gt * 16 + kc) * TILE_H + r * 64 + ((c8 ^ (r & 7)) << 3)) = hv;
}

// ---------------- merged w1+w2 -> tiled fp16, DST-LINEAR (coalesced writes)
__global__ __launch_bounds__(256) void cvt_w(
    const float* __restrict__ w1, const float* __restrict__ w2,
    _Float16* __restrict__ w1t, _Float16* __restrict__ w2t,
    int ch, int Fc, int lgnftl, int lgnkc, unsigned halfChunks)
{
  unsigned g = blockIdx.x * 256 + threadIdx.x;
  if (g < halfChunks) {
    unsigned tile = g >> 10;
    unsigned kc = tile & 15;
    unsigned et = tile >> 4;
    unsigned ftl = et & ((1u << lgnftl) - 1);
    unsigned e = et >> lgnftl;
    unsigned r = (g >> 3) & 127;
    unsigned sc = g & 7;
    unsigned c8 = sc ^ (r & 7);
    unsigned frow = ftl * 128 + r;
    const float4* s = reinterpret_cast<const float4*>(
        w1 + ((size_t)e * F_DIM + ch * Fc + frow) * C_DIM + kc * 64 + c8 * 8);
    *reinterpret_cast<half8*>(w1t + (size_t)g * 8) = cvt8(s[0], s[1]);
  } else {
    unsigned g2 = g - halfChunks;
    unsigned tile = g2 >> 10;
    unsigned kc = tile & ((1u << lgnkc) - 1);
    unsigned et = tile >> lgnkc;
    unsigned ct = et & 7;
    unsigned e = et >> 3;
    unsigned r = (g2 >> 3) & 127;
    unsigned sc = g2 & 7;
    unsigned c8 = sc ^ (r & 7);
    unsigned c = ct * 128 + r;
    const float4* s = reinterpret_cast<const float4*>(
        w2 + ((size_t)e * C_DIM + c) * F_DIM + ch * Fc + kc * 64 + c8 * 8);
    *reinterpret_cast<half8*>(w2t + (size_t)g2 * 8) = cvt8(s[0], s[1]);
  }
}

// ======== 256x256 2-phase machinery: dynamic LDS = 2 buf x 4 tiles x 16KB ========
// tile idx within buf: 0=A0, 1=A1, 2=B0, 3=B1
#define LDS_T(buf_, ix_) (lds + ((size_t)((buf_) * 4 + (ix_))) * TILE_H)

// full stage of one K-step into buffer buf_: 8 x 16B per thread
#define STAGE4(buf_, a0_, a1_, b0_, b1_)                                          \
  {                                                                               \
    _Pragma("unroll")                                                             \
    for (int i_ = 0; i_ < 2; ++i_) {                                              \
      int o_ = tid * 8 + i_ * 4096;                                               \
      __builtin_amdgcn_global_load_lds((const AS1 void*)((a0_) + o_),             \
          (AS3 void*)(LDS_T(buf_, 0) + o_), 16, 0, 0);                            \
      __builtin_amdgcn_global_load_lds((const AS1 void*)((a1_) + o_),             \
          (AS3 void*)(LDS_T(buf_, 1) + o_), 16, 0, 0);                            \
      __builtin_amdgcn_global_load_lds((const AS1 void*)((b0_) + o_),             \
          (AS3 void*)(LDS_T(buf_, 2) + o_), 16, 0, 0);                            \
      __builtin_amdgcn_global_load_lds((const AS1 void*)((b1_) + o_),             \
          (AS3 void*)(LDS_T(buf_, 3) + o_), 16, 0, 0);                            \
    }                                                                             \
  }

// SWAPPED operands: mfma(bF, aF) -> D rows = f/c (reg-indexed), cols = tokens.
// Wave (wr,wc): A rows [wr*128,+128) from A-tile wr; B cols [wc*64,+64) of 256.
#define COMPUTE256(buf_)                                                          \
  _Pragma("unroll")                                                               \
  for (int kk = 0; kk < 64; kk += 32) {                                           \
    const int klo = kk + (lane >> 4) * 8;                                         \
    half8 aF[8], bF[4];                                                           \
    const _Float16* aT_ = LDS_T(buf_, wr);                                        \
    const _Float16* bT_ = LDS_T(buf_, 2 + (wc >> 1));                             \
    _Pragma("unroll")                                                             \
    for (int m = 0; m < 8; ++m) {                                                 \
      int r = m * 16 + (lane & 15);                                               \
      aF[m] = *reinterpret_cast<const half8*>(&aT_[r * 64 + swz(r, klo)]);        \
    }                                                                             \
    _Pragma("unroll")                                                             \
    for (int n = 0; n < 4; ++n) {                                                 \
      int rb = (wc & 1) * 64 + n * 16 + (lane & 15);                              \
      bF[n] = *reinterpret_cast<const half8*>(&bT_[rb * 64 + swz(rb, klo)]);      \
    }                                                                             \
    _Pragma("unroll")                                                             \
    for (int m = 0; m < 8; ++m)                                                   \
      _Pragma("unroll")                                                           \
      for (int n = 0; n < 4; ++n)                                                 \
        acc[m][n] = __builtin_amdgcn_mfma_f32_16x16x32_f16(bF[n], aF[m], acc[m][n], 0, 0, 0); \
  }

// ---------------- GEMM1: ht[pos, f] = relu(xg[pos] . w1t[e][f] + b1)
__global__ __launch_bounds__(512, 2) void gemm1_kernel(
    const _Float16* __restrict__ xg, const _Float16* __restrict__ w1t,
    const float* __restrict__ b1, const int* __restrict__ tile_off,
    _Float16* __restrict__ ht, int ch, int Fc)
{
  extern __shared__ _Float16 lds[];
  const int NFT = Fc >> 8;
  const int wgid = xcd_swz(blockIdx.x, gridDim.x);
  const int grp = wgid / (4 * NFT);
  const int rem = wgid - grp * 4 * NFT;
  const int ft = rem >> 2;
  const int gt = (grp * 4 + (rem & 3)) * 2;
  if (gt >= tile_off[E_NUM]) return;
  int e = 0;
  while (gt >= tile_off[e + 1]) ++e;
  const int nftl = Fc >> 7;
  const _Float16* At0 = xg + (size_t)gt * 16 * TILE_H;
  const _Float16* At1 = xg + (size_t)(gt + 1) * 16 * TILE_H;
  const _Float16* Bt0 = w1t + (size_t)(e * nftl + 2 * ft) * 16 * TILE_H;
  const _Float16* Bt1 = w1t + (size_t)(e * nftl + 2 * ft + 1) * 16 * TILE_H;

  const int tid = threadIdx.x;
  const int lane = tid & 63;
  const int wave = tid >> 6;
  const int wr = wave >> 2, wc = wave & 3;

  f32x4 acc[8][4];
#pragma unroll
  for (int m = 0; m < 8; ++m)
#pragma unroll
    for (int n = 0; n < 4; ++n) acc[m][n] = (f32x4){0.f, 0.f, 0.f, 0.f};

  // 2-phase: prologue stage, then {stage next | compute cur | sync} per K-step
  STAGE4(0, At0, At1, Bt0, Bt1);
  __syncthreads();
  for (int kc = 0; kc < 16; ++kc) {
    const int cur = kc & 1;
    if (kc + 1 < 16) {
      size_t ko = (size_t)(kc + 1) * TILE_H;
      STAGE4(cur ^ 1, At0 + ko, At1 + ko, Bt0 + ko, Bt1 + ko);
    }
    COMPUTE256(cur);
    __syncthreads();   // drains vmcnt (next buf ready) + all waves done reading cur
  }

  // epilogue: lane holds 4 consecutive f per reg -> 8B stores (pad rows written, never read)
  const int nkcF = Fc >> 6;
  const int gtw = gt + wr;
  const float* b1e = b1 + e * F_DIM + ch * Fc;
#pragma unroll
  for (int m = 0; m < 8; ++m) {
    int tok = m * 16 + (lane & 15);
#pragma unroll
    for (int n = 0; n < 4; ++n) {
      int flb = ft * 256 + wc * 64 + n * 16 + ((lane >> 4) << 2);
      float4 bv = *reinterpret_cast<const float4*>(b1e + flb);
      half4 hv;
      hv[0] = (_Float16)fmaxf(acc[m][n][0] + bv.x, 0.f);
      hv[1] = (_Float16)fmaxf(acc[m][n][1] + bv.y, 0.f);
      hv[2] = (_Float16)fmaxf(acc[m][n][2] + bv.z, 0.f);
      hv[3] = (_Float16)fmaxf(acc[m][n][3] + bv.w, 0.f);
      *reinterpret_cast<half4*>(
          ht + ((size_t)gtw * nkcF + (flb >> 6)) * TILE_H + tok * 64 +
          ((((flb >> 3) & 7) ^ (tok & 7)) << 3) + (flb & 7)) = hv;
    }
  }
}

// ---------------- GEMM2: y[ks][pos][c] (+)= ht[pos] . w2t[e][c], kspl-way K-split
__global__ __launch_bounds__(512, 2) void gemm2_kernel(
    const _Float16* __restrict__ ht, const _Float16* __restrict__ w2t,
    const int* __restrict__ tile_off, _Float16* __restrict__ y,
    int Fc, int kspl, int accum)
{
  extern __shared__ _Float16 lds[];
  const int wgid = xcd_swz(blockIdx.x, gridDim.x);
  const int NCMB = 4 * kspl;
  const int grp = wgid / (4 * NCMB);
  const int rem = wgid - grp * 4 * NCMB;
  const int cmb = rem >> 2;
  const int gt = (grp * 4 + (rem & 3)) * 2;
  if (gt >= tile_off[E_NUM]) return;
  const int ct2 = cmb & 3;
  const int ks = cmb >> 2;
  int e = 0;
  while (gt >= tile_off[e + 1]) ++e;
  const int nkc = Fc >> 6;
  const int klen = nkc / kspl;
  const _Float16* At0 = ht + ((size_t)gt * nkc + ks * klen) * TILE_H;
  const _Float16* At1 = ht + ((size_t)(gt + 1) * nkc + ks * klen) * TILE_H;
  const _Float16* Bt0 = w2t + ((size_t)(e * 8 + 2 * ct2) * nkc + ks * klen) * TILE_H;
  const _Float16* Bt1 = w2t + ((size_t)(e * 8 + 2 * ct2 + 1) * nkc + ks * klen) * TILE_H;

  const int tid = threadIdx.x;
  const int lane = tid & 63;
  const int wave = tid >> 6;
  const int wr = wave >> 2, wc = wave & 3;

  f32x4 acc[8][4];
#pragma unroll
  for (int m = 0; m < 8; ++m)
#pragma unroll
    for (int n = 0; n < 4; ++n) acc[m][n] = (f32x4){0.f, 0.f, 0.f, 0.f};

  STAGE4(0, At0, At1, Bt0, Bt1);
  __syncthreads();
  for (int kc = 0; kc < klen; ++kc) {
    const int cur = kc & 1;
    if (kc + 1 < klen) {
      size_t ko = (size_t)(kc + 1) * TILE_H;
      STAGE4(cur ^ 1, At0 + ko, At1 + ko, Bt0 + ko, Bt1 + ko);
    }
    COMPUTE256(cur);
    __syncthreads();
  }

  _Float16* yk = y + ((size_t)(ks * MAXT + gt + wr) * 128) * C_DIM;
#pragma unroll
  for (int m = 0; m < 8; ++m) {
    int tok = m * 16 + (lane & 15);
#pragma unroll
    for (int n = 0; n < 4; ++n) {
      int cb = ct2 * 256 + wc * 64 + n * 16 + ((lane >> 4) << 2);
      half4* p = reinterpret_cast<half4*>(yk + (size_t)tok * C_DIM + cb);
      half4 hv;
      if (accum) {
        half4 old = *p;
        hv[0] = (_Float16)(acc[m][n][0] + (float)old[0]);
        hv[1] = (_Float16)(acc[m][n][1] + (float)old[1]);
        hv[2] = (_Float16)(acc[m][n][2] + (float)old[2]);
        hv[3] = (_Float16)(acc[m][n][3] + (float)old[3]);
      } else {
        hv[0] = (_Float16)acc[m][n][0];
        hv[1] = (_Float16)acc[m][n][1];
        hv[2] = (_Float16)acc[m][n][2];
        hv[3] = (_Float16)acc[m][n][3];
      }
      *p = hv;
    }
  }
}

// ---------------- Combine: out[t] = sum_k w_k * (b2[e_k] + sum_ks y[ks][pos_k])
__global__ __launch_bounds__(256) void combine_kernel(
    const _Float16* __restrict__ y, const int* __restrict__ inv,
    const float* __restrict__ top_w, const float* __restrict__ b2,
    float* __restrict__ out, int kspl)
{
  int g = blockIdx.x * 256 + threadIdx.x;
  int t = g >> 7, c8 = (g & 127) << 3;
  float o[8];
#pragma unroll
  for (int i = 0; i < 8; ++i) o[i] = 0.f;
#pragma unroll
  for (int k = 0; k < 2; ++k) {
    int iv = inv[t * 2 + k];
    int e = iv >> 16, pos = iv & 0xffff;
    float w = top_w[t * 2 + k];
    const float4* bb = reinterpret_cast<const float4*>(b2 + e * C_DIM + c8);
    float4 bv0 = bb[0], bv1 = bb[1];
    float s[8] = {bv0.x, bv0.y, bv0.z, bv0.w, bv1.x, bv1.y, bv1.z, bv1.w};
    for (int ks = 0; ks < kspl; ++ks) {
      half8 hv = *reinterpret_cast<const half8*>(
          y + ((size_t)(ks * MAXT * 128 + pos)) * C_DIM + c8);
#pragma unroll
      for (int i = 0; i < 8; ++i) s[i] += (float)hv[i];
    }
#pragma unroll
    for (int i = 0; i < 8; ++i) o[i] += w * s[i];
  }
  float4* op = reinterpret_cast<float4*>(out + (size_t)t * C_DIM + c8);
  op[0] = (float4){o[0], o[1], o[2], o[3]};
  op[1] = (float4){o[4], o[5], o[6], o[7]};
}

extern "C" void kernel_launch(void* const* d_in, const int* in_sizes, int n_in,
                              void* d_out, int out_size, void* d_ws, size_t ws_size,
                              hipStream_t stream)
{
  const float* x  = (const float*)d_in[0];
  const float* rw = (const float*)d_in[1];
  const float* w1 = (const float*)d_in[2];
  const float* b1 = (const float*)d_in[3];
  const float* w2 = (const float*)d_in[4];
  const float* b2 = (const float*)d_in[5];
  float* out = (float*)d_out;

  char* ws = (char*)d_ws;
  size_t off = 0;
  auto carve = [&](size_t bytes) -> void* {
    void* p = ws + off;
    off += (bytes + 255) & ~(size_t)255;
    return p;
  };
  int*   top_idx  = (int*)carve((size_t)T_TOK * 2 * sizeof(int));
  float* top_w    = (float*)carve((size_t)T_TOK * 2 * sizeof(float));
  int*   counts   = (int*)carve(E_NUM * sizeof(int));
  int*   tile_off = (int*)carve((E_NUM + 1) * sizeof(int));
  int*   rows_g   = (int*)carve((size_t)NP * sizeof(int));
  int*   inv      = (int*)carve((size_t)T_TOK * 2 * sizeof(int));
  _Float16* xg    = (_Float16*)carve((size_t)MAXT * 16 * TILE_H * sizeof(_Float16));
  _Float16* y     = (_Float16*)carve((size_t)4 * NP * C_DIM * sizeof(_Float16));
  size_t fixed = off;

  int nchunk = 8;
  const int cands[4] = {1, 2, 4, 8};
  for (int ci = 0; ci < 4; ++ci) {
    int n = cands[ci];
    size_t fc = (size_t)(F_DIM / n);
    size_t w1b = ((size_t)E_NUM * fc * C_DIM * 2 + 255) & ~(size_t)255;
    size_t w2b = ((size_t)E_NUM * C_DIM * fc * 2 + 255) & ~(size_t)255;
    size_t htb = ((size_t)MAXT * (fc >> 6) * TILE_H * 2 + 255) & ~(size_t)255;
    if (fixed + w1b + w2b + htb <= ws_size) { nchunk = n; break; }
  }
  const int Fc = F_DIM / nchunk;
  int lgFc = 0; while ((1 << lgFc) < Fc) ++lgFc;
  _Float16* w1t = (_Float16*)carve((size_t)E_NUM * Fc * C_DIM * sizeof(_Float16));
  _Float16* w2t = (_Float16*)carve((size_t)E_NUM * C_DIM * Fc * sizeof(_Float16));
  _Float16* ht  = (_Float16*)carve((size_t)MAXT * (Fc >> 6) * TILE_H * sizeof(_Float16));

  const int kspl = (Fc >= 2048) ? 4 : 2;
  const size_t dynLds = (size_t)8 * TILE_H * sizeof(_Float16);   // 128 KB

  router_kernel<<<T_TOK / 4, 256, 0, stream>>>(x, rw, top_idx, top_w);
  build_lists<<<1, 512, 0, stream>>>(top_idx, rows_g, counts, tile_off, inv);
  gather_x<<<(MAXT * 128 * 128) / 256, 256, 0, stream>>>(x, rows_g, counts, tile_off, xg);

  const unsigned halfChunks = (unsigned)Fc << 10;   // E*Fc*C/8
  for (int ch = 0; ch < nchunk; ++ch) {
    cvt_w<<<8 * Fc, 256, 0, stream>>>(w1, w2, w1t, w2t, ch, Fc, lgFc - 7, lgFc - 6, halfChunks);
    gemm1_kernel<<<(MAXT / 2) * (Fc / 256), 512, dynLds, stream>>>(
        xg, w1t, b1, tile_off, ht, ch, Fc);
    gemm2_kernel<<<(MAXT / 2) * 4 * kspl, 512, dynLds, stream>>>(
        ht, w2t, tile_off, y, Fc, kspl, ch != 0);
  }
  combine_kernel<<<(T_TOK * 128) / 256, 256, 0, stream>>>(y, inv, top_w, b2, out, kspl);
}